// Round 9
// baseline (377.045 us; speedup 1.0000x reference)
//
#include <hip/hip_runtime.h>

#define TT   512
#define HD   18
#define NBA  8           /* ACTIVE batches per block (grid = 4096/NBA = 512) */
#define NBL  16          /* LDS column count (MFMA tile width; cols NBA..15 dummy) */
#define NTH  256         /* 4 waves */
#define RS   68          /* LDS row stride in halves (136B: 8B-aligned, odd dwords) */

typedef _Float16 v8h __attribute__((ext_vector_type(8)));
typedef float    v4f __attribute__((ext_vector_type(4)));

__device__ __forceinline__ float fsig(float x) {
    return __builtin_amdgcn_rcpf(1.0f + __expf(-x));
}

// LDS rows (per buffer, per batch-col): k[0..17]=input (x or h1), k[18..35]=own h,
// k[36]=1.0 (bias column), k[37..67]=0.
// Buffers: SH[0..3] = layer-1 ring (x 3-ahead, h1 1-ahead); SH[4..5] = layer-2 dbuf.

template<int NT>
__device__ __forceinline__ void run_wave(
    int tbase, int isl1, int pfmode, int lane,
    const float* __restrict__ x,
    const float* __restrict__ wih, const float* __restrict__ whh,
    const float* __restrict__ bi,  const float* __restrict__ bh,
    float* __restrict__ out,
    _Float16 (*SH)[NBL][RS], size_t b0)
{
    const int rl = lane & 15;       // batch column
    const int lg = lane >> 4;       // k-group / h-subrow

    // ---- A fragments: W'[row=4h+g][k] , k: 0-17 wih, 18-35 whh, 36 bias ----
    v8h Af[NT][2];
    int hh[NT];
    #pragma unroll
    for (int i = 0; i < NT; ++i) {
        const int row = 16 * (tbase + i) + rl;
        const int h = row >> 2, g = row & 3;
        const int r = g * HD + h;
        #pragma unroll
        for (int s = 0; s < 2; ++s) {
            v8h a;
            #pragma unroll
            for (int j = 0; j < 8; ++j) {
                const int k = 8 * lg + j + 32 * s;
                float v = 0.f;
                if (h < HD) {
                    if (k < HD)            v = wih[r * HD + k];
                    else if (k < 2 * HD)   v = whh[r * HD + (k - HD)];
                    else if (k == 2 * HD)  v = bi[r] + bh[r];
                }
                a[j] = (_Float16)v;
            }
            Af[i][s] = a;
        }
        hh[i] = 4 * (tbase + i) + lg;   // this lane's h for tile i (C-layout)
    }

    // output pointers (used by layer-2 waves; only rl < NBA lanes store)
    float* op[NT];
    #pragma unroll
    for (int i = 0; i < NT; ++i)
        op[i] = out + (b0 + rl) * (size_t)TT * HD + hh[i];

    // ---- x-prefetch lane assignments (fixed elements, NBA*HD = 144 total) ----
    int pb[3] = {0,0,0}, pk[3] = {0,0,0}; bool pv[3] = {false,false,false};
    float xpf[3] = {0.f, 0.f, 0.f};
    if (pfmode) {
        int ee[3];
        ee[0] = (pfmode == 1) ? lane       : 128 + lane;
        ee[1] = (pfmode == 1) ? 64 + lane  : 192 + lane;
        ee[2] = 999;
        #pragma unroll
        for (int j = 0; j < 3; ++j) {
            pv[j] = ee[j] < NBA * HD;
            pb[j] = pv[j] ? ee[j] / HD : 0;
            pk[j] = pv[j] ? ee[j] % HD : 0;
            if (pv[j])   // preload x[3]
                xpf[j] = x[(b0 + pb[j]) * (size_t)TT * HD + 3 * HD + pk[j]];
        }
    }

    float cst[NT];
    #pragma unroll
    for (int i = 0; i < NT; ++i) cst[i] = 0.f;

    for (int n = 0; n <= TT; ++n) {
        const bool active = isl1 ? (n < TT) : (n >= 1);
        if (active) {
            const int bufi = isl1 ? (n & 3) : (4 + (n & 1));
            const _Float16* rowp = &SH[bufi][rl][0];
            v8h Bf[2];
            #pragma unroll
            for (int s = 0; s < 2; ++s) {
                union { uint2 u[2]; v8h v; } cv;
                cv.u[0] = *(const uint2*)(rowp + 8 * lg + 32 * s);
                cv.u[1] = *(const uint2*)(rowp + 8 * lg + 32 * s + 4);
                Bf[s] = cv.v;
            }
            const int wb1 = (n + 1) & 3;        // L1 ring slot for h1[n]
            const int wb2 = 4 + ((n + 1) & 1);  // L2 dbuf slot for next iter
            #pragma unroll
            for (int i = 0; i < NT; ++i) {
                v4f acc = {0.f, 0.f, 0.f, 0.f};
                acc = __builtin_amdgcn_mfma_f32_16x16x32_f16(Af[i][0], Bf[0], acc, 0, 0, 0);
                acc = __builtin_amdgcn_mfma_f32_16x16x32_f16(Af[i][1], Bf[1], acc, 0, 0, 0);
                const float gi = fsig(acc[0]);
                const float gf = fsig(acc[1]);
                const float gg = 2.f * fsig(2.f * acc[2]) - 1.f;   // tanh
                const float go = fsig(acc[3]);
                cst[i] = gf * cst[i] + gi * gg;
                const float th = 2.f * fsig(2.f * cst[i]) - 1.f;
                const float hv = go * th;
                const _Float16 h16 = (_Float16)hv;
                if (hh[i] < HD) {
                    if (isl1) {
                        SH[wb1][rl][HD + hh[i]] = h16;   // h1 -> own recurrence
                        SH[wb2][rl][hh[i]]      = h16;   // h1 -> layer-2 input
                    } else {
                        SH[wb2][rl][HD + hh[i]] = h16;   // h2 -> own recurrence
                        if (rl < NBA)
                            op[i][(size_t)(n - 1) * HD] = hv;  // final output h2[n-1]
                    }
                }
            }
        }
        // ---- deep x staging: store x[n+3] (held), load x[n+4] ----
        if (pfmode) {
            if (n + 3 < TT) {
                const int xb = (n + 3) & 3;
                #pragma unroll
                for (int j = 0; j < 3; ++j)
                    if (pv[j]) SH[xb][pb[j]][pk[j]] = (_Float16)xpf[j];
            }
            if (n + 4 < TT) {
                #pragma unroll
                for (int j = 0; j < 3; ++j)
                    if (pv[j]) xpf[j] = x[(b0 + pb[j]) * (size_t)TT * HD
                                          + (size_t)(n + 4) * HD + pk[j]];
            }
        }
        __syncthreads();
    }
}

__global__ __launch_bounds__(NTH) void lstm2_mfma2b(
    const float* __restrict__ x,
    const float* __restrict__ wih0, const float* __restrict__ whh0,
    const float* __restrict__ bih0, const float* __restrict__ bhh0,
    const float* __restrict__ wih1, const float* __restrict__ whh1,
    const float* __restrict__ bih1, const float* __restrict__ bhh1,
    float* __restrict__ out)
{
    __shared__ __align__(16) _Float16 SH[6][NBL][RS];

    const int tid  = threadIdx.x;
    const int wid  = tid >> 6;
    const int lane = tid & 63;
    const size_t b0 = (size_t)blockIdx.x * NBA;

    // ---- init: zero everything, set bias columns, fill x[0..2] ----
    {
        uint* shw = (uint*)&SH[0][0][0];            // 6*16*68/2 = 3264 dwords
        for (int i = tid; i < 6 * NBL * RS / 2; i += NTH) shw[i] = 0u;
        __syncthreads();
        for (int i = tid; i < 6 * NBL; i += NTH)
            SH[i / NBL][i % NBL][2 * HD] = (_Float16)1.0f;
        for (int i = tid; i < 3 * NBA * HD; i += NTH) {
            const int t = i / (NBA * HD), r2 = i % (NBA * HD);
            const int b = r2 / HD, k = r2 % HD;
            SH[t][b][k] = (_Float16)x[(b0 + b) * (size_t)TT * HD + t * HD + k];
        }
        __syncthreads();
    }

    if      (wid == 0) run_wave<3>(0, 1, 0, lane, x, wih0, whh0, bih0, bhh0, out, SH, b0);
    else if (wid == 1) run_wave<2>(3, 1, 1, lane, x, wih0, whh0, bih0, bhh0, out, SH, b0);
    else if (wid == 2) run_wave<3>(0, 0, 0, lane, x, wih1, whh1, bih1, bhh1, out, SH, b0);
    else               run_wave<2>(3, 0, 2, lane, x, wih1, whh1, bih1, bhh1, out, SH, b0);
}

extern "C" void kernel_launch(void* const* d_in, const int* in_sizes, int n_in,
                              void* d_out, int out_size, void* d_ws, size_t ws_size,
                              hipStream_t stream) {
    const float* x    = (const float*)d_in[0];
    const float* wih0 = (const float*)d_in[1];
    const float* whh0 = (const float*)d_in[2];
    const float* bih0 = (const float*)d_in[3];
    const float* bhh0 = (const float*)d_in[4];
    const float* wih1 = (const float*)d_in[5];
    const float* whh1 = (const float*)d_in[6];
    const float* bih1 = (const float*)d_in[7];
    const float* bhh1 = (const float*)d_in[8];
    float* out = (float*)d_out;
    (void)d_ws; (void)ws_size; (void)in_sizes; (void)n_in; (void)out_size;

    lstm2_mfma2b<<<dim3(4096 / NBA), dim3(NTH), 0, stream>>>(
        x, wih0, whh0, bih0, bhh0, wih1, whh1, bih1, bhh1, out);
}

// Round 10
// 365.776 us; speedup vs baseline: 1.0308x; 1.0308x over previous
//
#include <hip/hip_runtime.h>

#define TT   512
#define HD   18
#define NB   16          /* batches per block; grid = 256 */
#define NTH  384         /* 6 waves */
#define HRS  40          /* halves per h-row (80B): 18 h, [18]=1.0, rest 0 */
#define GRS  20          /* floats per G-row (80B) */

typedef _Float16 v8h __attribute__((ext_vector_type(8)));
typedef float    v4f __attribute__((ext_vector_type(4)));

__device__ __forceinline__ float fsig(float x) {
    return __builtin_amdgcn_rcpf(1.0f + __expf(-x));
}

// barrier with LDS-only drain: global loads/stores stay in flight
__device__ __forceinline__ void softbar() {
    asm volatile("s_waitcnt lgkmcnt(0)" ::: "memory");
    __builtin_amdgcn_s_barrier();
    asm volatile("" ::: "memory");
}

// A-fragment for one 16-row tile of the permuted (row = 4h+g) gate matrix.
// PROJ: k<18 -> wih[r][k], k==18 -> bi[r]+bh[r].  REC: k<18 -> whh[r][k].
template<bool PROJ>
__device__ __forceinline__ v8h build_A(int tile, int rl, int lg,
                                       const float* __restrict__ wm,
                                       const float* __restrict__ bi,
                                       const float* __restrict__ bh)
{
    const int row = 16 * tile + rl;
    const int h = row >> 2, g = row & 3;
    const int r = g * HD + h;
    v8h a;
    #pragma unroll
    for (int j = 0; j < 8; ++j) {
        const int k = 8 * lg + j;
        float v = 0.f;
        if (h < HD) {
            if (k < HD)               v = wm[r * HD + k];
            else if (PROJ && k == HD) v = bi[r] + bh[r];
        }
        a[j] = (_Float16)v;
    }
    return a;
}

__device__ __forceinline__ void load_x2(const float* __restrict__ base, int lg, float2* d) {
    if (lg < 2) {
        d[0] = *(const float2*)(base + 0);
        d[1] = *(const float2*)(base + 2);
        d[2] = *(const float2*)(base + 4);
        d[3] = *(const float2*)(base + 6);
    } else if (lg == 2) {
        d[0] = *(const float2*)(base + 0);
    }
}

__device__ __forceinline__ v8h pack_x(const float2* s, int lg) {
    v8h b;
    #pragma unroll
    for (int j = 0; j < 8; ++j) b[j] = (_Float16)0.f;
    if (lg < 2) {
        b[0] = (_Float16)s[0].x; b[1] = (_Float16)s[0].y;
        b[2] = (_Float16)s[1].x; b[3] = (_Float16)s[1].y;
        b[4] = (_Float16)s[2].x; b[5] = (_Float16)s[2].y;
        b[6] = (_Float16)s[3].x; b[7] = (_Float16)s[3].y;
    } else if (lg == 2) {
        b[0] = (_Float16)s[0].x; b[1] = (_Float16)s[0].y;
        b[2] = (_Float16)1.0f;              // bias column k=18
    }
    return b;
}

// ---- recurrent wave: NT tiles, one MFMA per tile, acc init from G buffer ----
template<int NT, bool ISL1>
__device__ __forceinline__ void rec_wave(
    int tbase, int lane,
    const float* __restrict__ whh,
    float* __restrict__ out, size_t b0,
    _Float16 (*hs)[NB][HRS],              // [2][NB][HRS] own-h rows
    const float (*gs)[5][NB][GRS])        // [2][5][NB][GRS] projection input
{
    const int rl = lane & 15, lg = lane >> 4;
    v8h A[NT];
    int hh[NT];
    float cst[NT];
    #pragma unroll
    for (int i = 0; i < NT; ++i) {
        A[i] = build_A<false>(tbase + i, rl, lg, whh, nullptr, nullptr);
        hh[i] = 4 * (tbase + i) + lg;
        cst[i] = 0.f;
    }
    float* op = out + (b0 + rl) * (size_t)TT * HD;

    constexpr int lo = ISL1 ? 1 : 3;
    constexpr int hi = ISL1 ? TT : TT + 2;

    for (int n = 0; n <= TT + 2; ++n) {
        if (n >= lo && n <= hi) {
            const _Float16* hrow = &hs[n & 1][rl][0];
            const v8h B = *(const v8h*)(hrow + 8 * lg);
            const int wp = (n + 1) & 1;
            #pragma unroll
            for (int i = 0; i < NT; ++i) {
                v4f acc = *(const v4f*)&gs[wp][tbase + i][rl][4 * lg];
                acc = __builtin_amdgcn_mfma_f32_16x16x32_f16(A[i], B, acc, 0, 0, 0);
                const float gi = fsig(acc[0]);
                const float gf = fsig(acc[1]);
                const float gg = 2.f * fsig(2.f * acc[2]) - 1.f;   // tanh
                const float go = fsig(acc[3]);
                cst[i] = gf * cst[i] + gi * gg;
                const float th = 2.f * fsig(2.f * cst[i]) - 1.f;
                const float hv = go * th;
                if (hh[i] < HD) {
                    hs[wp][rl][hh[i]] = (_Float16)hv;
                    if (!ISL1)
                        op[(size_t)(n - 3) * HD + hh[i]] = hv;
                }
            }
        }
        softbar();
    }
}

__global__ __launch_bounds__(NTH) void lstm2_split(
    const float* __restrict__ x,
    const float* __restrict__ wih0, const float* __restrict__ whh0,
    const float* __restrict__ bih0, const float* __restrict__ bhh0,
    const float* __restrict__ wih1, const float* __restrict__ whh1,
    const float* __restrict__ bih1, const float* __restrict__ bhh1,
    float* __restrict__ out)
{
    __shared__ __align__(16) _Float16 h1s[2][NB][HRS];
    __shared__ __align__(16) _Float16 h2s[2][NB][HRS];
    __shared__ __align__(16) float    gxs[2][5][NB][GRS];
    __shared__ __align__(16) float    ghs[2][5][NB][GRS];

    const int tid  = threadIdx.x;
    const int wid  = tid >> 6;
    const int lane = tid & 63;
    const int rl   = lane & 15, lg = lane >> 4;
    const size_t b0 = (size_t)blockIdx.x * NB;

    // ---- init: zero h rows, set bias columns ----
    {
        uint* hw = (uint*)&h1s[0][0][0];              // h1s+h2s contiguous? no — do each
        for (int i = tid; i < 2 * NB * HRS / 2; i += NTH) hw[i] = 0u;
        uint* hw2 = (uint*)&h2s[0][0][0];
        for (int i = tid; i < 2 * NB * HRS / 2; i += NTH) hw2[i] = 0u;
        __syncthreads();
        for (int i = tid; i < 2 * NB; i += NTH) {
            h1s[i / NB][i % NB][HD] = (_Float16)1.0f;
            h2s[i / NB][i % NB][HD] = (_Float16)1.0f;
        }
        __syncthreads();
    }

    if (wid == 0)      rec_wave<3, true >(0, lane, whh0, out, b0, h1s, gxs);
    else if (wid == 1) rec_wave<2, true >(3, lane, whh0, out, b0, h1s, gxs);
    else if (wid == 2) rec_wave<3, false>(0, lane, whh1, out, b0, h2s, ghs);
    else if (wid == 3) rec_wave<2, false>(3, lane, whh1, out, b0, h2s, ghs);
    else if (wid == 5) {
        // ---- Gh2 projection: Gh2[n-2] = Wih1 * h1[n-2] + b1, slots 2..TT+1 ----
        v8h A[5];
        #pragma unroll
        for (int i = 0; i < 5; ++i) A[i] = build_A<true>(i, rl, lg, wih1, bih1, bhh1);
        for (int n = 0; n <= TT + 2; ++n) {
            if (n >= 2 && n <= TT + 1) {
                const v8h B = *(const v8h*)(&h1s[n & 1][rl][0] + 8 * lg);
                const int wp = n & 1;
                #pragma unroll
                for (int i = 0; i < 5; ++i) {
                    v4f acc = {0.f, 0.f, 0.f, 0.f};
                    acc = __builtin_amdgcn_mfma_f32_16x16x32_f16(A[i], B, acc, 0, 0, 0);
                    *(v4f*)&ghs[wp][i][rl][4 * lg] = acc;
                }
            }
            softbar();
        }
    } else {
        // ---- Gx1 projection: Gx1[n] = Wih0 * x[n] + b0, slots 0..TT-1 ----
        v8h A[5];
        #pragma unroll
        for (int i = 0; i < 5; ++i) A[i] = build_A<true>(i, rl, lg, wih0, bih0, bhh0);
        const float* xb = x + (b0 + rl) * (size_t)TT * HD + 8 * lg;
        float2 xe[4], xo[4];
        load_x2(xb + 0 * HD, lg, xe);      // x[0]
        load_x2(xb + 1 * HD, lg, xo);      // x[1]
        for (int n = 0; n <= TT + 2; ++n) {
            if (n < TT) {
                const v8h B = (n & 1) ? pack_x(xo, lg) : pack_x(xe, lg);
                const int wp = n & 1;
                #pragma unroll
                for (int i = 0; i < 5; ++i) {
                    v4f acc = {0.f, 0.f, 0.f, 0.f};
                    acc = __builtin_amdgcn_mfma_f32_16x16x32_f16(A[i], B, acc, 0, 0, 0);
                    *(v4f*)&gxs[wp][i][rl][4 * lg] = acc;
                }
                if (n + 2 < TT) {
                    if (n & 1) load_x2(xb + (size_t)(n + 2) * HD, lg, xo);
                    else       load_x2(xb + (size_t)(n + 2) * HD, lg, xe);
                }
            }
            softbar();
        }
    }
}

extern "C" void kernel_launch(void* const* d_in, const int* in_sizes, int n_in,
                              void* d_out, int out_size, void* d_ws, size_t ws_size,
                              hipStream_t stream) {
    const float* x    = (const float*)d_in[0];
    const float* wih0 = (const float*)d_in[1];
    const float* whh0 = (const float*)d_in[2];
    const float* bih0 = (const float*)d_in[3];
    const float* bhh0 = (const float*)d_in[4];
    const float* wih1 = (const float*)d_in[5];
    const float* whh1 = (const float*)d_in[6];
    const float* bih1 = (const float*)d_in[7];
    const float* bhh1 = (const float*)d_in[8];
    float* out = (float*)d_out;
    (void)d_ws; (void)ws_size; (void)in_sizes; (void)n_in; (void)out_size;

    lstm2_split<<<dim3(4096 / NB), dim3(NTH), 0, stream>>>(
        x, wih0, whh0, bih0, bhh0, wih1, whh1, bih1, bhh1, out);
}